// Round 7
// baseline (235.595 us; speedup 1.0000x reference)
//
#include <hip/hip_runtime.h>

typedef __attribute__((ext_vector_type(4))) float f32x4;
typedef __attribute__((ext_vector_type(16))) float f32x16;
typedef __attribute__((ext_vector_type(8))) __bf16 bf16x8;
typedef __attribute__((ext_vector_type(4))) __bf16 bf16x4;
typedef __attribute__((ext_vector_type(2))) __bf16 bf16x2;
typedef __attribute__((ext_vector_type(4))) unsigned u32x4;

#define DEVINL __device__ __forceinline__

DEVINL void gld16(const void* g, void* l) {
  __builtin_amdgcn_global_load_lds((__attribute__((address_space(1))) void*)(void*)g,
                                   (__attribute__((address_space(3))) void*)l, 16, 0, 0);
}

// ---------------- cvt_w: W-transpose only (x-casts fused into gemm_proj) ----------------

__global__ __launch_bounds__(256) void cvt_w(const float* Wq, const float* Wk, const float* Wv,
                                             const float* Wo, __bf16* WT) {
  __shared__ float t[64][65];
  const int l = blockIdx.x;  // 256 blocks: z(4) x r(8) x c(8)
  const int z = l >> 6;
  const float* W = z == 0 ? Wq : z == 1 ? Wk : z == 2 ? Wv : Wo;
  __bf16* D = WT + (size_t)z * 512 * 512;
  const int r0 = ((l >> 3) & 7) * 64, c0 = (l & 7) * 64;
  const int tx = threadIdx.x & 63, ty = threadIdx.x >> 6;
#pragma unroll
  for (int j = 0; j < 16; ++j)
    t[ty + j * 4][tx] = W[(size_t)(r0 + ty + j * 4) * 512 + c0 + tx];
  __syncthreads();
#pragma unroll
  for (int j = 0; j < 16; ++j)
    D[(size_t)(c0 + ty + j * 4) * 512 + r0 + tx] = (__bf16)t[tx][ty + j * 4];
}

// ------- GEMM mainloop (fused f32->bf16 A): C[128,128] = cvt(A_f32[128,512]) * Bt^T, BK=64 -------

DEVINL void gemm_tile_f32(const float* A, const __bf16* Bt, int m0, int n0,
                          __bf16* As, __bf16* Bs, f32x4 acc[4][4]) {
  const int tid = threadIdx.x, lane = tid & 63, w = tid >> 6;
  const int qd = lane >> 4, r = lane & 15;
  const int wm = w & 1, wn = w >> 1;
  const char* bp[4];
#pragma unroll
  for (int j = 0; j < 4; ++j) {
    int c = (w * 4 + j) * 64 + lane;
    int row = c >> 3, gc = (c & 7) ^ (row & 7);
    bp[j] = (const char*)Bt + (size_t)(n0 + row) * 1024 + gc * 16;
  }
  const int am = tid >> 4, ac = tid & 15;
  const float* ap = A + (size_t)(m0 + am) * 512 + ac * 4;
  int woff[8];
#pragma unroll
  for (int j = 0; j < 8; ++j) {
    int m = j * 16 + am;
    woff[j] = m * 128 + (((ac >> 1) ^ (m & 7)) << 4) + ((ac & 1) << 3);
  }
  int offA[4][2], offB[4][2];
#pragma unroll
  for (int t = 0; t < 4; ++t)
#pragma unroll
    for (int ks = 0; ks < 2; ++ks) {
      int m = wm * 64 + t * 16 + r;
      offA[t][ks] = m * 128 + (((ks * 4 + qd) ^ (m & 7)) * 16);
      int n = wn * 64 + t * 16 + r;
      offB[t][ks] = n * 128 + (((ks * 4 + qd) ^ (n & 7)) * 16);
    }
  char* AsC = (char*)As;
  char* BsC = (char*)Bs;
  f32x4 areg[8];
  auto loadA = [&](int kt) {
#pragma unroll
    for (int j = 0; j < 8; ++j)
      areg[j] = *(const f32x4*)(ap + (size_t)j * 16 * 512 + kt * 64);
  };
  loadA(0);
  for (int kt = 0; kt < 8; ++kt) {
    __syncthreads();
#pragma unroll
    for (int j = 0; j < 8; ++j) {
      bf16x4 o;
#pragma unroll
      for (int g = 0; g < 4; ++g) o[g] = (__bf16)areg[j][g];
      *(bf16x4*)(AsC + woff[j]) = o;
    }
#pragma unroll
    for (int j = 0; j < 4; ++j) gld16(bp[j] + kt * 128, BsC + (w * 4 + j) * 1024);
    if (kt < 7) loadA(kt + 1);
    __syncthreads();
#pragma unroll
    for (int ks = 0; ks < 2; ++ks) {
      bf16x8 a[4], b[4];
#pragma unroll
      for (int t = 0; t < 4; ++t) {
        a[t] = *(const bf16x8*)(AsC + offA[t][ks]);
        b[t] = *(const bf16x8*)(BsC + offB[t][ks]);
      }
#pragma unroll
      for (int i = 0; i < 4; ++i)
#pragma unroll
        for (int j2 = 0; j2 < 4; ++j2)
          acc[i][j2] = __builtin_amdgcn_mfma_f32_16x16x32_bf16(a[i], b[j2], acc[i][j2], 0, 0, 0);
    }
  }
}

// z=0: Q[b][h][s][64] (pre-scaled by 0.125/ln2), z=1: K[b][h][s][64], z=2: Vt[b][h][dv][s]
__global__ __launch_bounds__(256, 3) void gemm_proj(const float* x1, const float* x2,
                                                    const float* x3, const __bf16* WT,
                                                    __bf16* Qo, __bf16* Ko, __bf16* Vto) {
  __shared__ __align__(16) char smem[34816];
  __bf16* As = (__bf16*)smem;
  __bf16* Bs = (__bf16*)(smem + 16384);
  const int z = blockIdx.z;
  const float* A = z == 0 ? x1 : z == 1 ? x2 : x3;
  const __bf16* Bt = WT + (size_t)z * 512 * 512;
  const int l = blockIdx.x;
  const int sidx = l >> 3;
  const int m0 = ((l & 7) * 8 + (sidx >> 2)) * 128;
  const int n0 = (sidx & 3) * 128;
  f32x4 acc[4][4] = {};
  gemm_tile_f32(A, Bt, m0, n0, As, Bs, acc);
  const int tid = threadIdx.x, lane = tid & 63, w = tid >> 6;
  const int qd = lane >> 4, r = lane & 15, wm = w & 1, wn = w >> 1;
  const int b = m0 >> 11, sbase = m0 & 2047;
  if (z == 2) {
    __syncthreads();
    char* T = smem;
#pragma unroll
    for (int mt = 0; mt < 4; ++mt)
#pragma unroll
      for (int nt = 0; nt < 4; ++nt) {
        int dv = wn * 64 + nt * 16 + r;
        int sl = wm * 64 + mt * 16 + qd * 4;
        bf16x4 p4;
#pragma unroll
        for (int g = 0; g < 4; ++g) p4[g] = (__bf16)acc[mt][nt][g];
        *(bf16x4*)(T + (size_t)dv * 272 + sl * 2) = p4;
      }
    __syncthreads();
#pragma unroll
    for (int p2 = 0; p2 < 2; ++p2) {
      int dvrow = p2 * 64 + (tid >> 2);
      int col = n0 + dvrow, h = col >> 6, d = col & 63;
      __bf16* dst = Vto + ((size_t)(b * 8 + h) * 64 + d) * 2048 + sbase + (tid & 3) * 8;
#pragma unroll
      for (int j = 0; j < 4; ++j) {
        bf16x8 vv = *(const bf16x8*)(T + (size_t)dvrow * 272 + (tid & 3) * 16 + j * 64);
        *(bf16x8*)(dst + j * 32) = vv;
      }
    }
  } else {
    const float qscale = 0.18033688f;  // 0.125 / ln(2): scores*0.125 via exp2
#pragma unroll
    for (int mt = 0; mt < 4; ++mt) {
#pragma unroll
      for (int nt = 0; nt < 4; ++nt) {
        f32x4 v = acc[mt][nt];
        if (z == 0) {
#pragma unroll
          for (int g = 0; g < 4; ++g) v[g] *= qscale;
        }
        int col = n0 + wn * 64 + nt * 16 + r;
        int h = col >> 6, d = col & 63;
        int s = sbase + wm * 64 + mt * 16 + qd * 4;
        __bf16* O = (z == 0 ? Qo : Ko) + ((size_t)(b * 8 + h) * 2048 + s) * 64 + d;
#pragma unroll
        for (int g = 0; g < 4; ++g) O[(size_t)g * 64] = (__bf16)v[g];
      }
    }
  }
}

// ---------------- gemm_out (fused combine): out = normalize(Opart) @ WoT^T + bo ----------------
__global__ __launch_bounds__(256, 2) void gemm_out(const __bf16* Op, const float* Lp,
                                                   const __bf16* WoT, const float* bo,
                                                   float* out) {
  __shared__ __align__(16) __bf16 As[64 * 64];
  __shared__ __align__(16) __bf16 Bs[128 * 64];
  const int tid = threadIdx.x, lane = tid & 63, w = tid >> 6;
  const int qd = lane >> 4, r = lane & 15, wm = w & 1, wn = w >> 1;
  const int id = blockIdx.x;
  const int rest = id >> 3;
  const int m0 = ((id & 7) * 16 + (rest & 15)) * 64;
  const int n0 = (rest >> 4) * 128;
  const int b8 = (m0 >> 11) * 8;
  const int sb = m0 & 2047;
  const char* bp[4];
#pragma unroll
  for (int j = 0; j < 4; ++j) {
    int c = (w * 4 + j) * 64 + lane;
    int row = c >> 3, gc = (c & 7) ^ (row & 7);
    bp[j] = (const char*)WoT + (size_t)(n0 + row) * 1024 + gc * 16;
  }
  int arow[2], ach[2];
#pragma unroll
  for (int j = 0; j < 2; ++j) {
    int c = (w * 2 + j) * 64 + lane;
    arow[j] = c >> 3;
    ach[j] = c & 7;
  }
  int offA[2][2], offB[4][2];
#pragma unroll
  for (int ks = 0; ks < 2; ++ks) {
#pragma unroll
    for (int t = 0; t < 2; ++t) {
      int m = wm * 32 + t * 16 + r;
      offA[t][ks] = m * 128 + (((ks * 4 + qd) ^ (m & 7)) * 16);
    }
#pragma unroll
    for (int t = 0; t < 4; ++t) {
      int n = wn * 64 + t * 16 + r;
      offB[t][ks] = n * 128 + (((ks * 4 + qd) ^ (n & 7)) * 16);
    }
  }
  char* AsC = (char*)As;
  char* BsC = (char*)Bs;
  bf16x8 pa0[2], pa1[2];
  float pinv[2];
  auto loadA = [&](int h) {
#pragma unroll
    for (int j = 0; j < 2; ++j) {
      size_t rr = (size_t)(b8 + h) * 2048 + sb + arow[j];
      const __bf16* p0 = Op + rr * 64 + ach[j] * 8;
      pa0[j] = *(const bf16x8*)p0;
      pa1[j] = *(const bf16x8*)(p0 + (size_t)32 * 2048 * 64);
      pinv[j] = 1.0f / (Lp[rr] + Lp[rr + 65536]);
    }
  };
  loadA(0);
  f32x4 acc[2][4] = {};
  for (int kt = 0; kt < 8; ++kt) {
    __syncthreads();
#pragma unroll
    for (int j = 0; j < 4; ++j) gld16(bp[j] + kt * 128, BsC + (w * 4 + j) * 1024);
#pragma unroll
    for (int j = 0; j < 2; ++j) {
      bf16x8 q;
#pragma unroll
      for (int k2 = 0; k2 < 8; ++k2)
        q[k2] = (__bf16)(((float)pa0[j][k2] + (float)pa1[j][k2]) * pinv[j]);
      *(bf16x8*)(AsC + arow[j] * 128 + (ach[j] ^ (arow[j] & 7)) * 16) = q;
    }
    __syncthreads();
    if (kt < 7) loadA(kt + 1);
#pragma unroll
    for (int ks = 0; ks < 2; ++ks) {
      bf16x8 a[2], b[4];
#pragma unroll
      for (int t = 0; t < 2; ++t) a[t] = *(const bf16x8*)(AsC + offA[t][ks]);
#pragma unroll
      for (int t = 0; t < 4; ++t) b[t] = *(const bf16x8*)(BsC + offB[t][ks]);
#pragma unroll
      for (int i = 0; i < 2; ++i)
#pragma unroll
        for (int j2 = 0; j2 < 4; ++j2)
          acc[i][j2] = __builtin_amdgcn_mfma_f32_16x16x32_bf16(a[i], b[j2], acc[i][j2], 0, 0, 0);
    }
  }
#pragma unroll
  for (int nt = 0; nt < 4; ++nt) {
    int col = n0 + wn * 64 + nt * 16 + r;
    float bv = bo[col];
#pragma unroll
    for (int mt = 0; mt < 2; ++mt) {
      int mg = m0 + wm * 32 + mt * 16 + qd * 4;
#pragma unroll
      for (int g = 0; g < 4; ++g) out[(size_t)(mg + g) * 512 + col] = acc[mt][nt][g] + bv;
    }
  }
}

// ---------------- attention v7: q-tile 256 x 8 waves, 128-key period, Q in registers ----------
// Grid 512 = 8 XCD x (4 bh-hi x 2 kvh x 8 q-tiles), 512 thr (8 waves), 2 blocks/CU (48KB LDS)
// -> 16 waves/CU (same TLP as v5) but HALF the barriers per key and half the staging issue.
// Verified pieces carried over: sigma K-staging (row bits 2<->3) making exp2+pack the exact PV
// A-fragment; he-XOR LDS swizzle; MFMA rowsum; 32x32x16 MFMA; D-layout epilogue maps.
// Per period (128 keys) per wave: 24 PV-MFMA + 16 QK-MFMA + 2 barriers + 4 gld16.
__global__ __launch_bounds__(512, 4) void attn(const __bf16* Q, const __bf16* K,
                                               const __bf16* Vt, __bf16* Opart, float* Lp) {
  __shared__ __align__(16) __bf16 Ksd[2][128 * 64];  // 2 x 16KB: double-buffered K period
  __shared__ __align__(16) __bf16 Vs[128 * 64];      // 16KB: single-buffered V period
  const int tid = threadIdx.x, lane = tid & 63, w = tid >> 6;  // w in 0..7
  const int l31 = lane & 31, lh = lane >> 5;
  const int id = blockIdx.x;
  const int rest = id >> 3;                  // 0..63
  const int bh = (id & 7) * 4 + (rest >> 4); // 0..31
  const int kvh = (rest >> 3) & 1;
  const int q0 = (rest & 7) * 256;
  const char* QgC = (const char*)Q + ((size_t)bh * 2048 + q0) * 128;
  const char* KgC = (const char*)K + (size_t)bh * 2048 * 128;
  const char* VgC = (const char*)Vt + (size_t)bh * 64 * 4096;
  char* VsC = (char*)Vs;
  char* Kc = (char*)Ksd;         // period being staged / consumed by PV-side QK
  char* Kn = (char*)Ksd + 16384; // period consumed by QK(next) this iteration

  // staging source/dest offsets: thread covers chunks (w*2+j), j=0,1 of a 16KB period region
  int ldso[2];
  const char* kst[2];  // K source (sigma'd row, pre-swizzled chunk), tile-local
  const char* vst[2];  // V source
#pragma unroll
  for (int j = 0; j < 2; ++j) {
    int o = ((w * 2 + j) * 64 + lane) * 16;  // linear dest offset in period region
    int tk = o >> 13;                         // tile within period (0/1)
    int oo = o & 8191;
    int m = oo >> 7;                          // LDS row within tile
    int cs = (oo >> 4) & 7;                   // dest 16B slot
    int gc = cs ^ (m & 7);                    // source chunk (read-side XOR inverse)
    int ms = (m & ~12) | ((m & 4) << 1) | ((m & 8) >> 1);  // sigma: swap row bits 2<->3
    kst[j] = KgC + (size_t)kvh * 16 * 8192 + (size_t)tk * 8192 + ms * 128 + gc * 16;
    vst[j] = VgC + (size_t)m * 4096 + (size_t)kvh * 16 * 128 + tk * 128 + gc * 16;
    ldso[j] = o;
  }

  // Q fragments DIRECT from global (no LDS): qf[c] = Q[q=w*32+l31][d=c*16+lh*8 ..+7]
  const int qrow = (w * 32 + l31) * 128;
  bf16x8 qf[4];
#pragma unroll
  for (int c = 0; c < 4; ++c)
    qf[c] = *(const bf16x8*)(QgC + qrow + c * 32 + lh * 16);

  // prologue staging: K period0 -> Kc, V period0 -> Vs, K period1 -> Kn
  gld16(kst[0], Kc + ldso[0]);
  gld16(kst[1], Kc + ldso[1]);
  gld16(vst[0], VsC + ldso[0]);
  gld16(vst[1], VsC + ldso[1]);
  gld16(kst[0] + 16384, Kn + ldso[0]);
  gld16(kst[1] + 16384, Kn + ldso[1]);
  __builtin_amdgcn_sched_barrier(0);
  asm volatile("s_waitcnt vmcnt(4)" ::: "memory");  // qf(4 loads)+K0(2) done; V0+K1 flying
  __builtin_amdgcn_sched_barrier(0);
  __builtin_amdgcn_s_barrier();
  __builtin_amdgcn_sched_barrier(0);

  const int rb = l31 * 128;
  const int he = (((lane & 7) ^ lh) << 4);

  bf16x8 ones;
#pragma unroll
  for (int j = 0; j < 8; ++j) ones[j] = (__bf16)1.0f;

  f32x16 oacc[2] = {};
  f32x16 lacc = {};
  bf16x8 pa[8];  // P fragments for one 128-key period (8 x 16-key chunks)

  auto smtile = [&](const f32x16& s, bf16x8& a0, bf16x8& a1) {
    unsigned wds[8];
#pragma unroll
    for (int i = 0; i < 8; ++i) {
      bf16x2 t;
      t[0] = (__bf16)__builtin_exp2f(s[2 * i]);
      t[1] = (__bf16)__builtin_exp2f(s[2 * i + 1]);
      wds[i] = __builtin_bit_cast(unsigned, t);
    }
    a0 = __builtin_bit_cast(bf16x8, (u32x4){wds[0], wds[1], wds[2], wds[3]});
    a1 = __builtin_bit_cast(bf16x8, (u32x4){wds[4], wds[5], wds[6], wds[7]});
  };
  auto qktile = [&](const char* base) {  // base -> one 32-key MFMA tile (keys on rows)
    f32x16 s = {};
#pragma unroll
    for (int c = 0; c < 4; ++c) {
      bf16x8 kf = *(const bf16x8*)(base + rb + ((c << 5) ^ he));
      s = __builtin_amdgcn_mfma_f32_32x32x16_bf16(kf, qf[c], s, 0, 0, 0);
    }
    return s;
  };

  // prologue compute: QK period0 from Kc -> pa (covers V0/K1 flight)
  {
    f32x16 s0 = qktile(Kc);
    smtile(s0, pa[0], pa[1]);
    f32x16 s1 = qktile(Kc + 4096);
    smtile(s1, pa[2], pa[3]);
    f32x16 s2 = qktile(Kc + 8192);
    smtile(s2, pa[4], pa[5]);
    f32x16 s3 = qktile(Kc + 12288);
    smtile(s3, pa[6], pa[7]);
  }
  __builtin_amdgcn_sched_barrier(0);
  asm volatile("s_waitcnt vmcnt(0)" ::: "memory");  // V0, K1 landed
  __builtin_amdgcn_sched_barrier(0);
  __builtin_amdgcn_s_barrier();
  __builtin_amdgcn_sched_barrier(0);

#pragma unroll 1
  for (int p = 0; p < 7; ++p) {
    // ---- interior: PV(period p) + QK(period p+1) + sm tiles 0..2 ----
    __builtin_amdgcn_s_setprio(1);
#pragma unroll
    for (int st = 0; st < 2; ++st)
#pragma unroll
      for (int c = 0; c < 4; ++c) {
        const int i = st * 4 + c;
        lacc = __builtin_amdgcn_mfma_f32_32x32x16_bf16(pa[i], ones, lacc, 0, 0, 0);
        bf16x8 vf0 = *(const bf16x8*)(VsC + st * 8192 + rb + ((c << 5) ^ he));
        oacc[0] = __builtin_amdgcn_mfma_f32_32x32x16_bf16(pa[i], vf0, oacc[0], 0, 0, 0);
        bf16x8 vf1 = *(const bf16x8*)(VsC + st * 8192 + 4096 + rb + ((c << 5) ^ he));
        oacc[1] = __builtin_amdgcn_mfma_f32_32x32x16_bf16(pa[i], vf1, oacc[1], 0, 0, 0);
      }
    f32x16 s0 = qktile(Kn);
    smtile(s0, pa[0], pa[1]);
    f32x16 s1 = qktile(Kn + 4096);
    smtile(s1, pa[2], pa[3]);
    f32x16 s2 = qktile(Kn + 8192);
    smtile(s2, pa[4], pa[5]);
    f32x16 s3 = qktile(Kn + 12288);
    __builtin_amdgcn_s_setprio(0);
    __builtin_amdgcn_sched_barrier(0);
    __builtin_amdgcn_s_barrier();  // all waves done reading Vs and Kn
    __builtin_amdgcn_sched_barrier(0);

    // ---- stage V(p+1) -> Vs, K(p+2) -> Kc; flight covered by sm tile 3 ----
    gld16(vst[0] + (size_t)(p + 1) * 256, VsC + ldso[0]);
    gld16(vst[1] + (size_t)(p + 1) * 256, VsC + ldso[1]);
    if (p < 6) {
      gld16(kst[0] + (size_t)(p + 2) * 16384, Kc + ldso[0]);
      gld16(kst[1] + (size_t)(p + 2) * 16384, Kc + ldso[1]);
    }
    __builtin_amdgcn_sched_barrier(0);
    smtile(s3, pa[6], pa[7]);
    __builtin_amdgcn_sched_barrier(0);
    asm volatile("s_waitcnt vmcnt(0)" ::: "memory");
    __builtin_amdgcn_sched_barrier(0);
    __builtin_amdgcn_s_barrier();  // publish
    __builtin_amdgcn_sched_barrier(0);

    char* tmp = Kc;
    Kc = Kn;
    Kn = tmp;
  }

  // epilogue: PV(period 7)
#pragma unroll
  for (int st = 0; st < 2; ++st)
#pragma unroll
    for (int c = 0; c < 4; ++c) {
      const int i = st * 4 + c;
      lacc = __builtin_amdgcn_mfma_f32_32x32x16_bf16(pa[i], ones, lacc, 0, 0, 0);
      bf16x8 vf0 = *(const bf16x8*)(VsC + st * 8192 + rb + ((c << 5) ^ he));
      oacc[0] = __builtin_amdgcn_mfma_f32_32x32x16_bf16(pa[i], vf0, oacc[0], 0, 0, 0);
      bf16x8 vf1 = *(const bf16x8*)(VsC + st * 8192 + 4096 + rb + ((c << 5) ^ he));
      oacc[1] = __builtin_amdgcn_mfma_f32_32x32x16_bf16(pa[i], vf1, oacc[1], 0, 0, 0);
    }

  // lacc[g]: rowsum for q_local = (g&3)+8*(g>>2)+4*lh, identical across l31 lanes
  const size_t pbase = (size_t)(kvh * 32 + bh) * 2048;
  if (l31 == 0) {
#pragma unroll
    for (int g = 0; g < 16; ++g)
      Lp[pbase + q0 + w * 32 + (g & 3) + 8 * (g >> 2) + 4 * lh] = lacc[g];
  }
  // unnormalized O partial: lane holds q_local = (g&3)+8*(g>>2)+4*lh, dv = dvt*32 + l31
  __bf16* Ob0 = Opart + pbase * 64;
#pragma unroll
  for (int dvt = 0; dvt < 2; ++dvt) {
#pragma unroll
    for (int g = 0; g < 16; ++g) {
      int s = q0 + w * 32 + (g & 3) + 8 * (g >> 2) + 4 * lh;
      Ob0[(size_t)s * 64 + dvt * 32 + l31] = (__bf16)oacc[dvt][g];
    }
  }
}

// ---------------- host ----------------

extern "C" void kernel_launch(void* const* d_in, const int* in_sizes, int n_in,
                              void* d_out, int out_size, void* d_ws, size_t ws_size,
                              hipStream_t stream) {
  const float* x1 = (const float*)d_in[0];
  const float* x2 = (const float*)d_in[1];
  const float* x3 = (const float*)d_in[2];
  const float* Wq = (const float*)d_in[3];
  const float* Wk = (const float*)d_in[4];
  const float* Wv = (const float*)d_in[5];
  const float* Wo = (const float*)d_in[6];
  const float* bo = (const float*)d_in[7];
  float* out = (float*)d_out;
  char* ws = (char*)d_ws;
  const size_t MB = 1ull << 20;
  __bf16* WT = (__bf16*)(ws + 24 * MB);
  __bf16* Qb = (__bf16*)(ws + 26 * MB);
  __bf16* Kb = (__bf16*)(ws + 34 * MB);
  __bf16* Vtb = (__bf16*)(ws + 42 * MB);
  __bf16* Opart = (__bf16*)(ws + 58 * MB);
  float* Lp = (float*)(ws + 74 * MB);

  cvt_w<<<dim3(256), 256, 0, stream>>>(Wq, Wk, Wv, Wo, WT);
  gemm_proj<<<dim3(256, 1, 3), 256, 0, stream>>>(x1, x2, x3, WT, Qb, Kb, Vtb);
  attn<<<dim3(512), 512, 0, stream>>>(Qb, Kb, Vtb, Opart, Lp);
  gemm_out<<<dim3(512), 256, 0, stream>>>(Opart, Lp, WT + 3ull * 512 * 512, bo, out);
}

// Round 8
// 208.032 us; speedup vs baseline: 1.1325x; 1.1325x over previous
//
#include <hip/hip_runtime.h>

typedef __attribute__((ext_vector_type(4))) float f32x4;
typedef __attribute__((ext_vector_type(16))) float f32x16;
typedef __attribute__((ext_vector_type(8))) __bf16 bf16x8;
typedef __attribute__((ext_vector_type(4))) __bf16 bf16x4;
typedef __attribute__((ext_vector_type(2))) __bf16 bf16x2;
typedef __attribute__((ext_vector_type(4))) unsigned u32x4;

#define DEVINL __device__ __forceinline__

DEVINL void gld16(const void* g, void* l) {
  __builtin_amdgcn_global_load_lds((__attribute__((address_space(1))) void*)(void*)g,
                                   (__attribute__((address_space(3))) void*)l, 16, 0, 0);
}

// ---------------- cvt_w: W-transpose only (x-casts fused into gemm_proj) ----------------

__global__ __launch_bounds__(256) void cvt_w(const float* Wq, const float* Wk, const float* Wv,
                                             const float* Wo, __bf16* WT) {
  __shared__ float t[64][65];
  const int l = blockIdx.x;  // 256 blocks: z(4) x r(8) x c(8)
  const int z = l >> 6;
  const float* W = z == 0 ? Wq : z == 1 ? Wk : z == 2 ? Wv : Wo;
  __bf16* D = WT + (size_t)z * 512 * 512;
  const int r0 = ((l >> 3) & 7) * 64, c0 = (l & 7) * 64;
  const int tx = threadIdx.x & 63, ty = threadIdx.x >> 6;
#pragma unroll
  for (int j = 0; j < 16; ++j)
    t[ty + j * 4][tx] = W[(size_t)(r0 + ty + j * 4) * 512 + c0 + tx];
  __syncthreads();
#pragma unroll
  for (int j = 0; j < 16; ++j)
    D[(size_t)(c0 + ty + j * 4) * 512 + r0 + tx] = (__bf16)t[tx][ty + j * 4];
}

// ------- GEMM mainloop (fused f32->bf16 A): C[128,128] = cvt(A_f32[128,512]) * Bt^T, BK=64 -------

DEVINL void gemm_tile_f32(const float* A, const __bf16* Bt, int m0, int n0,
                          __bf16* As, __bf16* Bs, f32x4 acc[4][4]) {
  const int tid = threadIdx.x, lane = tid & 63, w = tid >> 6;
  const int qd = lane >> 4, r = lane & 15;
  const int wm = w & 1, wn = w >> 1;
  const char* bp[4];
#pragma unroll
  for (int j = 0; j < 4; ++j) {
    int c = (w * 4 + j) * 64 + lane;
    int row = c >> 3, gc = (c & 7) ^ (row & 7);
    bp[j] = (const char*)Bt + (size_t)(n0 + row) * 1024 + gc * 16;
  }
  const int am = tid >> 4, ac = tid & 15;
  const float* ap = A + (size_t)(m0 + am) * 512 + ac * 4;
  int woff[8];
#pragma unroll
  for (int j = 0; j < 8; ++j) {
    int m = j * 16 + am;
    woff[j] = m * 128 + (((ac >> 1) ^ (m & 7)) << 4) + ((ac & 1) << 3);
  }
  int offA[4][2], offB[4][2];
#pragma unroll
  for (int t = 0; t < 4; ++t)
#pragma unroll
    for (int ks = 0; ks < 2; ++ks) {
      int m = wm * 64 + t * 16 + r;
      offA[t][ks] = m * 128 + (((ks * 4 + qd) ^ (m & 7)) * 16);
      int n = wn * 64 + t * 16 + r;
      offB[t][ks] = n * 128 + (((ks * 4 + qd) ^ (n & 7)) * 16);
    }
  char* AsC = (char*)As;
  char* BsC = (char*)Bs;
  f32x4 areg[8];
  auto loadA = [&](int kt) {
#pragma unroll
    for (int j = 0; j < 8; ++j)
      areg[j] = *(const f32x4*)(ap + (size_t)j * 16 * 512 + kt * 64);
  };
  loadA(0);
  for (int kt = 0; kt < 8; ++kt) {
    __syncthreads();
#pragma unroll
    for (int j = 0; j < 8; ++j) {
      bf16x4 o;
#pragma unroll
      for (int g = 0; g < 4; ++g) o[g] = (__bf16)areg[j][g];
      *(bf16x4*)(AsC + woff[j]) = o;
    }
#pragma unroll
    for (int j = 0; j < 4; ++j) gld16(bp[j] + kt * 128, BsC + (w * 4 + j) * 1024);
    if (kt < 7) loadA(kt + 1);
    __syncthreads();
#pragma unroll
    for (int ks = 0; ks < 2; ++ks) {
      bf16x8 a[4], b[4];
#pragma unroll
      for (int t = 0; t < 4; ++t) {
        a[t] = *(const bf16x8*)(AsC + offA[t][ks]);
        b[t] = *(const bf16x8*)(BsC + offB[t][ks]);
      }
#pragma unroll
      for (int i = 0; i < 4; ++i)
#pragma unroll
        for (int j2 = 0; j2 < 4; ++j2)
          acc[i][j2] = __builtin_amdgcn_mfma_f32_16x16x32_bf16(a[i], b[j2], acc[i][j2], 0, 0, 0);
    }
  }
}

// z=0: Q[b][h][s][64] (pre-scaled by 0.125/ln2), z=1: K[b][h][s][64], z=2: Vt[b][h][dv][s]
__global__ __launch_bounds__(256, 3) void gemm_proj(const float* x1, const float* x2,
                                                    const float* x3, const __bf16* WT,
                                                    __bf16* Qo, __bf16* Ko, __bf16* Vto) {
  __shared__ __align__(16) char smem[34816];
  __bf16* As = (__bf16*)smem;
  __bf16* Bs = (__bf16*)(smem + 16384);
  const int z = blockIdx.z;
  const float* A = z == 0 ? x1 : z == 1 ? x2 : x3;
  const __bf16* Bt = WT + (size_t)z * 512 * 512;
  const int l = blockIdx.x;
  const int sidx = l >> 3;
  const int m0 = ((l & 7) * 8 + (sidx >> 2)) * 128;
  const int n0 = (sidx & 3) * 128;
  f32x4 acc[4][4] = {};
  gemm_tile_f32(A, Bt, m0, n0, As, Bs, acc);
  const int tid = threadIdx.x, lane = tid & 63, w = tid >> 6;
  const int qd = lane >> 4, r = lane & 15, wm = w & 1, wn = w >> 1;
  const int b = m0 >> 11, sbase = m0 & 2047;
  if (z == 2) {
    __syncthreads();
    char* T = smem;
#pragma unroll
    for (int mt = 0; mt < 4; ++mt)
#pragma unroll
      for (int nt = 0; nt < 4; ++nt) {
        int dv = wn * 64 + nt * 16 + r;
        int sl = wm * 64 + mt * 16 + qd * 4;
        bf16x4 p4;
#pragma unroll
        for (int g = 0; g < 4; ++g) p4[g] = (__bf16)acc[mt][nt][g];
        *(bf16x4*)(T + (size_t)dv * 272 + sl * 2) = p4;
      }
    __syncthreads();
#pragma unroll
    for (int p2 = 0; p2 < 2; ++p2) {
      int dvrow = p2 * 64 + (tid >> 2);
      int col = n0 + dvrow, h = col >> 6, d = col & 63;
      __bf16* dst = Vto + ((size_t)(b * 8 + h) * 64 + d) * 2048 + sbase + (tid & 3) * 8;
#pragma unroll
      for (int j = 0; j < 4; ++j) {
        bf16x8 vv = *(const bf16x8*)(T + (size_t)dvrow * 272 + (tid & 3) * 16 + j * 64);
        *(bf16x8*)(dst + j * 32) = vv;
      }
    }
  } else {
    const float qscale = 0.18033688f;  // 0.125 / ln(2): scores*0.125 via exp2
#pragma unroll
    for (int mt = 0; mt < 4; ++mt) {
#pragma unroll
      for (int nt = 0; nt < 4; ++nt) {
        f32x4 v = acc[mt][nt];
        if (z == 0) {
#pragma unroll
          for (int g = 0; g < 4; ++g) v[g] *= qscale;
        }
        int col = n0 + wn * 64 + nt * 16 + r;
        int h = col >> 6, d = col & 63;
        int s = sbase + wm * 64 + mt * 16 + qd * 4;
        __bf16* O = (z == 0 ? Qo : Ko) + ((size_t)(b * 8 + h) * 2048 + s) * 64 + d;
#pragma unroll
        for (int g = 0; g < 4; ++g) O[(size_t)g * 64] = (__bf16)v[g];
      }
    }
  }
}

// ---------------- gemm_out (fused combine): out = normalize(Opart) @ WoT^T + bo ----------------
__global__ __launch_bounds__(256, 2) void gemm_out(const __bf16* Op, const float* Lp,
                                                   const __bf16* WoT, const float* bo,
                                                   float* out) {
  __shared__ __align__(16) __bf16 As[64 * 64];
  __shared__ __align__(16) __bf16 Bs[128 * 64];
  const int tid = threadIdx.x, lane = tid & 63, w = tid >> 6;
  const int qd = lane >> 4, r = lane & 15, wm = w & 1, wn = w >> 1;
  const int id = blockIdx.x;
  const int rest = id >> 3;
  const int m0 = ((id & 7) * 16 + (rest & 15)) * 64;
  const int n0 = (rest >> 4) * 128;
  const int b8 = (m0 >> 11) * 8;
  const int sb = m0 & 2047;
  const char* bp[4];
#pragma unroll
  for (int j = 0; j < 4; ++j) {
    int c = (w * 4 + j) * 64 + lane;
    int row = c >> 3, gc = (c & 7) ^ (row & 7);
    bp[j] = (const char*)WoT + (size_t)(n0 + row) * 1024 + gc * 16;
  }
  int arow[2], ach[2];
#pragma unroll
  for (int j = 0; j < 2; ++j) {
    int c = (w * 2 + j) * 64 + lane;
    arow[j] = c >> 3;
    ach[j] = c & 7;
  }
  int offA[2][2], offB[4][2];
#pragma unroll
  for (int ks = 0; ks < 2; ++ks) {
#pragma unroll
    for (int t = 0; t < 2; ++t) {
      int m = wm * 32 + t * 16 + r;
      offA[t][ks] = m * 128 + (((ks * 4 + qd) ^ (m & 7)) * 16);
    }
#pragma unroll
    for (int t = 0; t < 4; ++t) {
      int n = wn * 64 + t * 16 + r;
      offB[t][ks] = n * 128 + (((ks * 4 + qd) ^ (n & 7)) * 16);
    }
  }
  char* AsC = (char*)As;
  char* BsC = (char*)Bs;
  bf16x8 pa0[2], pa1[2];
  float pinv[2];
  auto loadA = [&](int h) {
#pragma unroll
    for (int j = 0; j < 2; ++j) {
      size_t rr = (size_t)(b8 + h) * 2048 + sb + arow[j];
      const __bf16* p0 = Op + rr * 64 + ach[j] * 8;
      pa0[j] = *(const bf16x8*)p0;
      pa1[j] = *(const bf16x8*)(p0 + (size_t)32 * 2048 * 64);
      pinv[j] = 1.0f / (Lp[rr] + Lp[rr + 65536]);
    }
  };
  loadA(0);
  f32x4 acc[2][4] = {};
  for (int kt = 0; kt < 8; ++kt) {
    __syncthreads();
#pragma unroll
    for (int j = 0; j < 4; ++j) gld16(bp[j] + kt * 128, BsC + (w * 4 + j) * 1024);
#pragma unroll
    for (int j = 0; j < 2; ++j) {
      bf16x8 q;
#pragma unroll
      for (int k2 = 0; k2 < 8; ++k2)
        q[k2] = (__bf16)(((float)pa0[j][k2] + (float)pa1[j][k2]) * pinv[j]);
      *(bf16x8*)(AsC + arow[j] * 128 + (ach[j] ^ (arow[j] & 7)) * 16) = q;
    }
    __syncthreads();
    if (kt < 7) loadA(kt + 1);
#pragma unroll
    for (int ks = 0; ks < 2; ++ks) {
      bf16x8 a[2], b[4];
#pragma unroll
      for (int t = 0; t < 2; ++t) a[t] = *(const bf16x8*)(AsC + offA[t][ks]);
#pragma unroll
      for (int t = 0; t < 4; ++t) b[t] = *(const bf16x8*)(BsC + offB[t][ks]);
#pragma unroll
      for (int i = 0; i < 2; ++i)
#pragma unroll
        for (int j2 = 0; j2 < 4; ++j2)
          acc[i][j2] = __builtin_amdgcn_mfma_f32_16x16x32_bf16(a[i], b[j2], acc[i][j2], 0, 0, 0);
    }
  }
#pragma unroll
  for (int nt = 0; nt < 4; ++nt) {
    int col = n0 + wn * 64 + nt * 16 + r;
    float bv = bo[col];
#pragma unroll
    for (int mt = 0; mt < 2; ++mt) {
      int mg = m0 + wm * 32 + mt * 16 + qd * 4;
#pragma unroll
      for (int g = 0; g < 4; ++g) out[(size_t)(mg + g) * 512 + col] = acc[mt][nt][g] + bv;
    }
  }
}

// ---------------- attention v8: r5 geometry + V direct-from-L2 (no V LDS), 1 barrier/iter -------
// Grid 1024 = 8 XCD x (4 bh x 2 kvh x 16 q-tiles), 4 blocks/CU (LDS 32KB), proven L2-local
// (r5 FETCH 13.9MB). Verified dataflow: sigma K-staging (row bits 2<->3) -> exp2+pack IS the PV
// A-fragment; he-XOR K swizzle; MFMA rowsum; 32x32x16.
// NEW: V is NOT staged (L2-resident, 256KB/bh shared by 16 blocks/XCD). PV B-fragments load
// directly: vf(dvt,c) = Vt[dv = dvt*32+l31][key chunk c*32 + lh*16] (chunk map (2c)^lh = c*32+lh*16,
// derived from the r5 swizzle algebra). Removes 2 gld16 + 16 ds_reads + ONE BARRIER per iter:
//   iter: stage K(t+2)->Kc | PV(t) w/ global vf + QK(t+1) from Kn + softmax | vmcnt(0) | barrier
__global__ __launch_bounds__(256, 4) void attn(const __bf16* Q, const __bf16* K,
                                               const __bf16* Vt, __bf16* Opart, float* Lp) {
  __shared__ __align__(16) __bf16 Qs[128 * 64];     // 16KB, prologue only
  __shared__ __align__(16) __bf16 Ksd[2][64 * 64];  // 16KB double-buffered K
  const int tid = threadIdx.x, lane = tid & 63, w = tid >> 6;
  const int l31 = lane & 31, lh = lane >> 5;
  const int id = blockIdx.x;
  const int rest = id >> 3;
  const int bh = (id & 7) * 4 + (rest >> 5);
  const int kvh = (rest >> 4) & 1;
  const int q0 = (rest & 15) * 128;
  const char* QgC = (const char*)(Q + ((size_t)bh * 2048 + q0) * 64);
  const char* KgC = (const char*)(K + (size_t)bh * 2048 * 64);
  const char* VgC = (const char*)(Vt + (size_t)bh * 64 * 2048);
  char* QsC = (char*)Qs;
  char* Kc = (char*)Ksd;
  char* Kn = (char*)Ksd + 8192;

  // K staging offsets (sigma'd source row, pre-swizzled chunk; linear LDS dest)
  int koff[2], ldso[2];
#pragma unroll
  for (int j = 0; j < 2; ++j) {
    int c = (w * 2 + j) * 64 + lane;
    int m = c >> 3, gc = (c & 7) ^ (m & 7);
    int ms = (m & ~12) | ((m & 4) << 1) | ((m & 8) >> 1);  // sigma: swap row bits 2<->3
    koff[j] = ms * 128 + gc * 16;
    ldso[j] = (w * 2 + j) * 1024;
  }

  const int kt0 = kvh * 16;
  const size_t kb = (size_t)kt0 * 8192;

  // prologue staging: Q(4) -> Qs, K(0)->Kc, K(1)->Kn
#pragma unroll
  for (int j = 0; j < 4; ++j) {
    int c = (w * 4 + j) * 64 + lane;
    int m = c >> 3, gc = (c & 7) ^ (m & 7);
    gld16(QgC + m * 128 + gc * 16, QsC + (w * 4 + j) * 1024);
  }
  gld16(KgC + kb + koff[0], Kc + ldso[0]);
  gld16(KgC + kb + koff[1], Kc + ldso[1]);
  gld16(KgC + kb + 8192 + koff[0], Kn + ldso[0]);
  gld16(KgC + kb + 8192 + koff[1], Kn + ldso[1]);
  __builtin_amdgcn_sched_barrier(0);
  asm volatile("s_waitcnt vmcnt(2)" ::: "memory");  // Q + K(0) landed; K(1) flying
  __builtin_amdgcn_sched_barrier(0);
  __builtin_amdgcn_s_barrier();
  __builtin_amdgcn_sched_barrier(0);

  const int rb = l31 * 128;
  const int he = (((lane & 7) ^ lh) << 4);
  const int qrow = (w * 32 + l31) * 128;

  // Q fragments hoisted (Qs dead afterwards)
  bf16x8 qf[4];
#pragma unroll
  for (int c = 0; c < 4; ++c) qf[c] = *(const bf16x8*)(QsC + qrow + ((c << 5) ^ he));

  // V direct-read pointers: lane covers dv = dvt*32 + l31, key chunk c*32 + lh*16 within tile
  const char* vp0 = VgC + (size_t)l31 * 4096 + lh * 16 + (size_t)kt0 * 128;
  const char* vp1 = vp0 + (size_t)32 * 4096;

  bf16x8 ones;
#pragma unroll
  for (int j = 0; j < 8; ++j) ones[j] = (__bf16)1.0f;

  f32x16 oacc[2] = {};
  f32x16 lacc = {};
  bf16x8 pa[4];

  auto smhalf = [&](const f32x16& s, bf16x8& a0, bf16x8& a1) {
    unsigned wds[8];
#pragma unroll
    for (int i = 0; i < 8; ++i) {
      bf16x2 t;
      t[0] = (__bf16)__builtin_exp2f(s[2 * i]);
      t[1] = (__bf16)__builtin_exp2f(s[2 * i + 1]);
      wds[i] = __builtin_bit_cast(unsigned, t);
    }
    a0 = __builtin_bit_cast(bf16x8, (u32x4){wds[0], wds[1], wds[2], wds[3]});
    a1 = __builtin_bit_cast(bf16x8, (u32x4){wds[4], wds[5], wds[6], wds[7]});
  };
  auto qkchain = [&](const char* Kb, int half) {
    f32x16 s = {};
#pragma unroll
    for (int c = 0; c < 4; ++c) {
      bf16x8 kf = *(const bf16x8*)(Kb + half * 4096 + rb + ((c << 5) ^ he));
      s = __builtin_amdgcn_mfma_f32_32x32x16_bf16(kf, qf[c], s, 0, 0, 0);
    }
    return s;
  };

  // prologue compute: QK(0) -> pa (covers K(1) flight)
  {
    f32x16 s0 = qkchain(Kc, 0);
    f32x16 s1 = qkchain(Kc, 1);
    smhalf(s0, pa[0], pa[1]);
    smhalf(s1, pa[2], pa[3]);
  }
  __builtin_amdgcn_sched_barrier(0);
  asm volatile("s_waitcnt vmcnt(0)" ::: "memory");  // K(1) landed
  __builtin_amdgcn_sched_barrier(0);
  __builtin_amdgcn_s_barrier();
  __builtin_amdgcn_sched_barrier(0);

#pragma unroll 1
  for (int t = 0; t < 15; ++t) {
    // stage K(t+2) into Kc (its K(t) contents were consumed pre-barrier last iter)
    if (t < 14) {
      gld16(KgC + kb + (size_t)(t + 2) * 8192 + koff[0], Kc + ldso[0]);
      gld16(KgC + kb + (size_t)(t + 2) * 8192 + koff[1], Kc + ldso[1]);
    }
    __builtin_amdgcn_sched_barrier(0);

    // PV(t) with direct-global V + QK(t+1) from Kn, softmax interleaved
    __builtin_amdgcn_s_setprio(1);
#pragma unroll
    for (int c = 0; c < 4; ++c) {
      lacc = __builtin_amdgcn_mfma_f32_32x32x16_bf16(pa[c], ones, lacc, 0, 0, 0);
      bf16x8 vf0 = *(const bf16x8*)(vp0 + c * 32);
      oacc[0] = __builtin_amdgcn_mfma_f32_32x32x16_bf16(pa[c], vf0, oacc[0], 0, 0, 0);
      bf16x8 vf1 = *(const bf16x8*)(vp1 + c * 32);
      oacc[1] = __builtin_amdgcn_mfma_f32_32x32x16_bf16(pa[c], vf1, oacc[1], 0, 0, 0);
    }
    f32x16 s0 = qkchain(Kn, 0);
    f32x16 s1 = qkchain(Kn, 1);
    smhalf(s0, pa[0], pa[1]);
    __builtin_amdgcn_s_setprio(0);
    smhalf(s1, pa[2], pa[3]);

    __builtin_amdgcn_sched_barrier(0);
    asm volatile("s_waitcnt vmcnt(0)" ::: "memory");  // K(t+2) landed
    __builtin_amdgcn_sched_barrier(0);
    __builtin_amdgcn_s_barrier();  // single barrier per iteration
    __builtin_amdgcn_sched_barrier(0);

    char* tmp = Kc;
    Kc = Kn;
    Kn = tmp;
    vp0 += 128;
    vp1 += 128;
  }

  // epilogue: PV(15)
#pragma unroll
  for (int c = 0; c < 4; ++c) {
    lacc = __builtin_amdgcn_mfma_f32_32x32x16_bf16(pa[c], ones, lacc, 0, 0, 0);
    bf16x8 vf0 = *(const bf16x8*)(vp0 + c * 32);
    oacc[0] = __builtin_amdgcn_mfma_f32_32x32x16_bf16(pa[c], vf0, oacc[0], 0, 0, 0);
    bf16x8 vf1 = *(const bf16x8*)(vp1 + c * 32);
    oacc[1] = __builtin_amdgcn_mfma_f32_32x32x16_bf16(pa[c], vf1, oacc[1], 0, 0, 0);
  }

  // lacc[g]: rowsum for q_local = (g&3)+8*(g>>2)+4*lh, identical across l31 lanes
  const size_t pbase = (size_t)(kvh * 32 + bh) * 2048;
  if (l31 == 0) {
#pragma unroll
    for (int g = 0; g < 16; ++g)
      Lp[pbase + q0 + w * 32 + (g & 3) + 8 * (g >> 2) + 4 * lh] = lacc[g];
  }
  // unnormalized O partial: lane holds q_local = (g&3)+8*(g>>2)+4*lh, dv = dvt*32 + l31
  __bf16* Ob0 = Opart + pbase * 64;
#pragma unroll
  for (int dvt = 0; dvt < 2; ++dvt) {
#pragma unroll
    for (int g = 0; g < 16; ++g) {
      int s = q0 + w * 32 + (g & 3) + 8 * (g >> 2) + 4 * lh;
      Ob0[(size_t)s * 64 + dvt * 32 + l31] = (__bf16)oacc[dvt][g];
    }
  }
}

// ---------------- host ----------------

extern "C" void kernel_launch(void* const* d_in, const int* in_sizes, int n_in,
                              void* d_out, int out_size, void* d_ws, size_t ws_size,
                              hipStream_t stream) {
  const float* x1 = (const float*)d_in[0];
  const float* x2 = (const float*)d_in[1];
  const float* x3 = (const float*)d_in[2];
  const float* Wq = (const float*)d_in[3];
  const float* Wk = (const float*)d_in[4];
  const float* Wv = (const float*)d_in[5];
  const float* Wo = (const float*)d_in[6];
  const float* bo = (const float*)d_in[7];
  float* out = (float*)d_out;
  char* ws = (char*)d_ws;
  const size_t MB = 1ull << 20;
  __bf16* WT = (__bf16*)(ws + 24 * MB);
  __bf16* Qb = (__bf16*)(ws + 26 * MB);
  __bf16* Kb = (__bf16*)(ws + 34 * MB);
  __bf16* Vtb = (__bf16*)(ws + 42 * MB);
  __bf16* Opart = (__bf16*)(ws + 58 * MB);
  float* Lp = (float*)(ws + 74 * MB);

  cvt_w<<<dim3(256), 256, 0, stream>>>(Wq, Wk, Wv, Wo, WT);
  gemm_proj<<<dim3(256, 1, 3), 256, 0, stream>>>(x1, x2, x3, WT, Qb, Kb, Vtb);
  attn<<<dim3(1024), 256, 0, stream>>>(Qb, Kb, Vtb, Opart, Lp);
  gemm_out<<<dim3(512), 256, 0, stream>>>(Opart, Lp, WT + 3ull * 512 * 512, bo, out);
}

// Round 9
// 183.729 us; speedup vs baseline: 1.2823x; 1.1323x over previous
//
#include <hip/hip_runtime.h>

typedef __attribute__((ext_vector_type(4))) float f32x4;
typedef __attribute__((ext_vector_type(16))) float f32x16;
typedef __attribute__((ext_vector_type(8))) __bf16 bf16x8;
typedef __attribute__((ext_vector_type(4))) __bf16 bf16x4;
typedef __attribute__((ext_vector_type(2))) __bf16 bf16x2;
typedef __attribute__((ext_vector_type(4))) unsigned u32x4;

#define DEVINL __device__ __forceinline__

DEVINL void gld16(const void* g, void* l) {
  __builtin_amdgcn_global_load_lds((__attribute__((address_space(1))) void*)(void*)g,
                                   (__attribute__((address_space(3))) void*)l, 16, 0, 0);
}

// ---------------- cvt_w: W-transpose only (x-casts fused into gemm_proj) ----------------

__global__ __launch_bounds__(256) void cvt_w(const float* Wq, const float* Wk, const float* Wv,
                                             const float* Wo, __bf16* WT) {
  __shared__ float t[64][65];
  const int l = blockIdx.x;  // 256 blocks: z(4) x r(8) x c(8)
  const int z = l >> 6;
  const float* W = z == 0 ? Wq : z == 1 ? Wk : z == 2 ? Wv : Wo;
  __bf16* D = WT + (size_t)z * 512 * 512;
  const int r0 = ((l >> 3) & 7) * 64, c0 = (l & 7) * 64;
  const int tx = threadIdx.x & 63, ty = threadIdx.x >> 6;
#pragma unroll
  for (int j = 0; j < 16; ++j)
    t[ty + j * 4][tx] = W[(size_t)(r0 + ty + j * 4) * 512 + c0 + tx];
  __syncthreads();
#pragma unroll
  for (int j = 0; j < 16; ++j)
    D[(size_t)(c0 + ty + j * 4) * 512 + r0 + tx] = (__bf16)t[tx][ty + j * 4];
}

// ------- GEMM mainloop (fused f32->bf16 A): C[128,128] = cvt(A_f32[128,512]) * Bt^T, BK=64 -------

DEVINL void gemm_tile_f32(const float* A, const __bf16* Bt, int m0, int n0,
                          __bf16* As, __bf16* Bs, f32x4 acc[4][4]) {
  const int tid = threadIdx.x, lane = tid & 63, w = tid >> 6;
  const int qd = lane >> 4, r = lane & 15;
  const int wm = w & 1, wn = w >> 1;
  const char* bp[4];
#pragma unroll
  for (int j = 0; j < 4; ++j) {
    int c = (w * 4 + j) * 64 + lane;
    int row = c >> 3, gc = (c & 7) ^ (row & 7);
    bp[j] = (const char*)Bt + (size_t)(n0 + row) * 1024 + gc * 16;
  }
  const int am = tid >> 4, ac = tid & 15;
  const float* ap = A + (size_t)(m0 + am) * 512 + ac * 4;
  int woff[8];
#pragma unroll
  for (int j = 0; j < 8; ++j) {
    int m = j * 16 + am;
    woff[j] = m * 128 + (((ac >> 1) ^ (m & 7)) << 4) + ((ac & 1) << 3);
  }
  int offA[4][2], offB[4][2];
#pragma unroll
  for (int t = 0; t < 4; ++t)
#pragma unroll
    for (int ks = 0; ks < 2; ++ks) {
      int m = wm * 64 + t * 16 + r;
      offA[t][ks] = m * 128 + (((ks * 4 + qd) ^ (m & 7)) * 16);
      int n = wn * 64 + t * 16 + r;
      offB[t][ks] = n * 128 + (((ks * 4 + qd) ^ (n & 7)) * 16);
    }
  char* AsC = (char*)As;
  char* BsC = (char*)Bs;
  f32x4 areg[8];
  auto loadA = [&](int kt) {
#pragma unroll
    for (int j = 0; j < 8; ++j)
      areg[j] = *(const f32x4*)(ap + (size_t)j * 16 * 512 + kt * 64);
  };
  loadA(0);
  for (int kt = 0; kt < 8; ++kt) {
    __syncthreads();
    // issue B global->LDS first so the vmem flight overlaps the A cast+ds_write VALU phase
#pragma unroll
    for (int j = 0; j < 4; ++j) gld16(bp[j] + kt * 128, BsC + (w * 4 + j) * 1024);
#pragma unroll
    for (int j = 0; j < 8; ++j) {
      bf16x4 o;
#pragma unroll
      for (int g = 0; g < 4; ++g) o[g] = (__bf16)areg[j][g];
      *(bf16x4*)(AsC + woff[j]) = o;
    }
    if (kt < 7) loadA(kt + 1);
    __syncthreads();
#pragma unroll
    for (int ks = 0; ks < 2; ++ks) {
      bf16x8 a[4], b[4];
#pragma unroll
      for (int t = 0; t < 4; ++t) {
        a[t] = *(const bf16x8*)(AsC + offA[t][ks]);
        b[t] = *(const bf16x8*)(BsC + offB[t][ks]);
      }
#pragma unroll
      for (int i = 0; i < 4; ++i)
#pragma unroll
        for (int j2 = 0; j2 < 4; ++j2)
          acc[i][j2] = __builtin_amdgcn_mfma_f32_16x16x32_bf16(a[i], b[j2], acc[i][j2], 0, 0, 0);
    }
  }
}

// z=0: Q[b][h][s][64] (pre-scaled by 0.125/ln2), z=1: K[b][h][s][64], z=2: Vt[b][h][dv][s]
__global__ __launch_bounds__(256, 3) void gemm_proj(const float* x1, const float* x2,
                                                    const float* x3, const __bf16* WT,
                                                    __bf16* Qo, __bf16* Ko, __bf16* Vto) {
  __shared__ __align__(16) char smem[34816];
  __bf16* As = (__bf16*)smem;
  __bf16* Bs = (__bf16*)(smem + 16384);
  const int z = blockIdx.z;
  const float* A = z == 0 ? x1 : z == 1 ? x2 : x3;
  const __bf16* Bt = WT + (size_t)z * 512 * 512;
  const int l = blockIdx.x;
  const int sidx = l >> 3;
  const int m0 = ((l & 7) * 8 + (sidx >> 2)) * 128;
  const int n0 = (sidx & 3) * 128;
  f32x4 acc[4][4] = {};
  gemm_tile_f32(A, Bt, m0, n0, As, Bs, acc);
  const int tid = threadIdx.x, lane = tid & 63, w = tid >> 6;
  const int qd = lane >> 4, r = lane & 15, wm = w & 1, wn = w >> 1;
  const int b = m0 >> 11, sbase = m0 & 2047;
  if (z == 2) {
    __syncthreads();
    char* T = smem;
#pragma unroll
    for (int mt = 0; mt < 4; ++mt)
#pragma unroll
      for (int nt = 0; nt < 4; ++nt) {
        int dv = wn * 64 + nt * 16 + r;
        int sl = wm * 64 + mt * 16 + qd * 4;
        bf16x4 p4;
#pragma unroll
        for (int g = 0; g < 4; ++g) p4[g] = (__bf16)acc[mt][nt][g];
        *(bf16x4*)(T + (size_t)dv * 272 + sl * 2) = p4;
      }
    __syncthreads();
#pragma unroll
    for (int p2 = 0; p2 < 2; ++p2) {
      int dvrow = p2 * 64 + (tid >> 2);
      int col = n0 + dvrow, h = col >> 6, d = col & 63;
      __bf16* dst = Vto + ((size_t)(b * 8 + h) * 64 + d) * 2048 + sbase + (tid & 3) * 8;
#pragma unroll
      for (int j = 0; j < 4; ++j) {
        bf16x8 vv = *(const bf16x8*)(T + (size_t)dvrow * 272 + (tid & 3) * 16 + j * 64);
        *(bf16x8*)(dst + j * 32) = vv;
      }
    }
  } else {
    const float qscale = 0.18033688f;  // 0.125 / ln(2): scores*0.125 via exp2
#pragma unroll
    for (int mt = 0; mt < 4; ++mt) {
#pragma unroll
      for (int nt = 0; nt < 4; ++nt) {
        f32x4 v = acc[mt][nt];
        if (z == 0) {
#pragma unroll
          for (int g = 0; g < 4; ++g) v[g] *= qscale;
        }
        int col = n0 + wn * 64 + nt * 16 + r;
        int h = col >> 6, d = col & 63;
        int s = sbase + wm * 64 + mt * 16 + qd * 4;
        __bf16* O = (z == 0 ? Qo : Ko) + ((size_t)(b * 8 + h) * 2048 + s) * 64 + d;
#pragma unroll
        for (int g = 0; g < 4; ++g) O[(size_t)g * 64] = (__bf16)v[g];
      }
    }
  }
}

// ---------------- gemm_out (fused combine): out = normalize(Opart) @ WoT^T + bo ----------------
__global__ __launch_bounds__(256, 2) void gemm_out(const __bf16* Op, const float* Lp,
                                                   const __bf16* WoT, const float* bo,
                                                   float* out) {
  __shared__ __align__(16) __bf16 As[64 * 64];
  __shared__ __align__(16) __bf16 Bs[128 * 64];
  const int tid = threadIdx.x, lane = tid & 63, w = tid >> 6;
  const int qd = lane >> 4, r = lane & 15, wm = w & 1, wn = w >> 1;
  const int id = blockIdx.x;
  const int rest = id >> 3;
  const int m0 = ((id & 7) * 16 + (rest & 15)) * 64;
  const int n0 = (rest >> 4) * 128;
  const int b8 = (m0 >> 11) * 8;
  const int sb = m0 & 2047;
  const char* bp[4];
#pragma unroll
  for (int j = 0; j < 4; ++j) {
    int c = (w * 4 + j) * 64 + lane;
    int row = c >> 3, gc = (c & 7) ^ (row & 7);
    bp[j] = (const char*)WoT + (size_t)(n0 + row) * 1024 + gc * 16;
  }
  int arow[2], ach[2];
#pragma unroll
  for (int j = 0; j < 2; ++j) {
    int c = (w * 2 + j) * 64 + lane;
    arow[j] = c >> 3;
    ach[j] = c & 7;
  }
  int offA[2][2], offB[4][2];
#pragma unroll
  for (int ks = 0; ks < 2; ++ks) {
#pragma unroll
    for (int t = 0; t < 2; ++t) {
      int m = wm * 32 + t * 16 + r;
      offA[t][ks] = m * 128 + (((ks * 4 + qd) ^ (m & 7)) * 16);
    }
#pragma unroll
    for (int t = 0; t < 4; ++t) {
      int n = wn * 64 + t * 16 + r;
      offB[t][ks] = n * 128 + (((ks * 4 + qd) ^ (n & 7)) * 16);
    }
  }
  char* AsC = (char*)As;
  char* BsC = (char*)Bs;
  bf16x8 pa0[2], pa1[2];
  float pinv[2];
  auto loadA = [&](int h) {
#pragma unroll
    for (int j = 0; j < 2; ++j) {
      size_t rr = (size_t)(b8 + h) * 2048 + sb + arow[j];
      const __bf16* p0 = Op + rr * 64 + ach[j] * 8;
      pa0[j] = *(const bf16x8*)p0;
      pa1[j] = *(const bf16x8*)(p0 + (size_t)32 * 2048 * 64);
      pinv[j] = 1.0f / (Lp[rr] + Lp[rr + 65536]);
    }
  };
  loadA(0);
  f32x4 acc[2][4] = {};
  for (int kt = 0; kt < 8; ++kt) {
    __syncthreads();
#pragma unroll
    for (int j = 0; j < 4; ++j) gld16(bp[j] + kt * 128, BsC + (w * 4 + j) * 1024);
#pragma unroll
    for (int j = 0; j < 2; ++j) {
      bf16x8 q;
#pragma unroll
      for (int k2 = 0; k2 < 8; ++k2)
        q[k2] = (__bf16)(((float)pa0[j][k2] + (float)pa1[j][k2]) * pinv[j]);
      *(bf16x8*)(AsC + arow[j] * 128 + (ach[j] ^ (arow[j] & 7)) * 16) = q;
    }
    __syncthreads();
    if (kt < 7) loadA(kt + 1);  // prefetch next head's partials under the MFMA phase
#pragma unroll
    for (int ks = 0; ks < 2; ++ks) {
      bf16x8 a[2], b[4];
#pragma unroll
      for (int t = 0; t < 2; ++t) a[t] = *(const bf16x8*)(AsC + offA[t][ks]);
#pragma unroll
      for (int t = 0; t < 4; ++t) b[t] = *(const bf16x8*)(BsC + offB[t][ks]);
#pragma unroll
      for (int i = 0; i < 2; ++i)
#pragma unroll
        for (int j2 = 0; j2 < 4; ++j2)
          acc[i][j2] = __builtin_amdgcn_mfma_f32_16x16x32_bf16(a[i], b[j2], acc[i][j2], 0, 0, 0);
    }
  }
#pragma unroll
  for (int nt = 0; nt < 4; ++nt) {
    int col = n0 + wn * 64 + nt * 16 + r;
    float bv = bo[col];
#pragma unroll
    for (int mt = 0; mt < 2; ++mt) {
      int mg = m0 + wm * 32 + mt * 16 + qd * 4;
#pragma unroll
      for (int g = 0; g < 4; ++g) out[(size_t)(mg + g) * 512 + col] = acc[mt][nt][g] + bv;
    }
  }
}

// ---------------- attention (r5 version, verified best: ~58.5us; structural plateau) ----------
// Grid 1024 = 8 XCD x (4 bh x 2 kvh x 16 q-tiles), 4 blocks/CU (LDS 40KB). Sigma K-staging
// (row bits 2<->3) -> exp2+pack IS the PV A-fragment; he-XOR swizzle; MFMA rowsum; 32x32x16.
// K double-buffered, V LDS-staged (coalesced gld16; direct-L2 V regressed 60% in r8).
__global__ __launch_bounds__(256, 4) void attn(const __bf16* Q, const __bf16* K,
                                               const __bf16* Vt, __bf16* Opart, float* Lp) {
  __shared__ __align__(16) __bf16 Qs[128 * 64];     // 16KB persistent Q tile
  __shared__ __align__(16) __bf16 Ksd[2][64 * 64];  // 16KB double-buffered K
  __shared__ __align__(16) __bf16 Vs[64 * 64];      // 8KB single-buffered V
  const int tid = threadIdx.x, lane = tid & 63, w = tid >> 6;
  const int l31 = lane & 31, lh = lane >> 5;
  const int id = blockIdx.x;
  const int rest = id >> 3;
  const int bh = (id & 7) * 4 + (rest >> 5);
  const int kvh = (rest >> 4) & 1;
  const int q0 = (rest & 15) * 128;
  const char* QgC = (const char*)(Q + ((size_t)bh * 2048 + q0) * 64);
  const char* KgC = (const char*)(K + (size_t)bh * 2048 * 64);
  const char* VgC = (const char*)(Vt + (size_t)bh * 64 * 2048);
  char* QsC = (char*)Qs;
  char* VsC = (char*)Vs;
  char* Kc = (char*)Ksd;
  char* Kn = (char*)Ksd + 8192;

  int koff[2], voff[2], ldso[2];
#pragma unroll
  for (int j = 0; j < 2; ++j) {
    int c = (w * 2 + j) * 64 + lane;
    int m = c >> 3, gc = (c & 7) ^ (m & 7);
    int ms = (m & ~12) | ((m & 4) << 1) | ((m & 8) >> 1);  // sigma: swap row bits 2<->3
    koff[j] = ms * 128 + gc * 16;
    voff[j] = m * 4096 + gc * 16;
    ldso[j] = (w * 2 + j) * 1024;
  }

  const int kt0 = kvh * 16;
  const size_t kb = (size_t)kt0 * 8192;
  const size_t vb = (size_t)kt0 * 128;

#pragma unroll
  for (int j = 0; j < 4; ++j) {
    int c = (w * 4 + j) * 64 + lane;
    int m = c >> 3, gc = (c & 7) ^ (m & 7);
    gld16(QgC + m * 128 + gc * 16, QsC + (w * 4 + j) * 1024);
  }
  gld16(KgC + kb + koff[0], Kc + ldso[0]);
  gld16(KgC + kb + koff[1], Kc + ldso[1]);
  gld16(VgC + vb + voff[0], VsC + ldso[0]);
  gld16(VgC + vb + voff[1], VsC + ldso[1]);
  gld16(KgC + kb + 8192 + koff[0], Kn + ldso[0]);
  gld16(KgC + kb + 8192 + koff[1], Kn + ldso[1]);
  __builtin_amdgcn_sched_barrier(0);
  asm volatile("s_waitcnt vmcnt(2)" ::: "memory");
  __builtin_amdgcn_sched_barrier(0);
  __builtin_amdgcn_s_barrier();
  __builtin_amdgcn_sched_barrier(0);

  const int rb = l31 * 128;
  const int he = (((lane & 7) ^ lh) << 4);
  const int qrow = (w * 32 + l31) * 128;

  bf16x8 ones;
#pragma unroll
  for (int j = 0; j < 8; ++j) ones[j] = (__bf16)1.0f;

  f32x16 oacc[2] = {};
  f32x16 lacc = {};
  bf16x8 pa[4];

  auto smhalf = [&](const f32x16& s, bf16x8& pa0, bf16x8& pa1) {
    unsigned wds[8];
#pragma unroll
    for (int i = 0; i < 8; ++i) {
      bf16x2 t;
      t[0] = (__bf16)__builtin_exp2f(s[2 * i]);
      t[1] = (__bf16)__builtin_exp2f(s[2 * i + 1]);
      wds[i] = __builtin_bit_cast(unsigned, t);
    }
    pa0 = __builtin_bit_cast(bf16x8, (u32x4){wds[0], wds[1], wds[2], wds[3]});
    pa1 = __builtin_bit_cast(bf16x8, (u32x4){wds[4], wds[5], wds[6], wds[7]});
  };
  auto qkchain = [&](const char* Kb, int half, const bf16x8 qf[4]) {
    f32x16 s = {};
#pragma unroll
    for (int c = 0; c < 4; ++c) {
      bf16x8 kf = *(const bf16x8*)(Kb + half * 4096 + rb + ((c << 5) ^ he));
      s = __builtin_amdgcn_mfma_f32_32x32x16_bf16(kf, qf[c], s, 0, 0, 0);
    }
    return s;
  };

  {
    bf16x8 qf[4];
#pragma unroll
    for (int c = 0; c < 4; ++c) qf[c] = *(const bf16x8*)(QsC + qrow + ((c << 5) ^ he));
    f32x16 s0 = qkchain(Kc, 0, qf);
    f32x16 s1 = qkchain(Kc, 1, qf);
    smhalf(s0, pa[0], pa[1]);
    smhalf(s1, pa[2], pa[3]);
  }
  __builtin_amdgcn_sched_barrier(0);
  asm volatile("s_waitcnt vmcnt(0)" ::: "memory");
  __builtin_amdgcn_sched_barrier(0);
  __builtin_amdgcn_s_barrier();
  __builtin_amdgcn_sched_barrier(0);

#pragma unroll 1
  for (int t = 0; t < 15; ++t) {
    __builtin_amdgcn_s_setprio(1);
#pragma unroll
    for (int c = 0; c < 4; ++c) {
      lacc = __builtin_amdgcn_mfma_f32_32x32x16_bf16(pa[c], ones, lacc, 0, 0, 0);
      bf16x8 vf0 = *(const bf16x8*)(VsC + rb + ((c << 5) ^ he));
      oacc[0] = __builtin_amdgcn_mfma_f32_32x32x16_bf16(pa[c], vf0, oacc[0], 0, 0, 0);
      bf16x8 vf1 = *(const bf16x8*)(VsC + 4096 + rb + ((c << 5) ^ he));
      oacc[1] = __builtin_amdgcn_mfma_f32_32x32x16_bf16(pa[c], vf1, oacc[1], 0, 0, 0);
    }
    bf16x8 qf[4];
#pragma unroll
    for (int c = 0; c < 4; ++c) qf[c] = *(const bf16x8*)(QsC + qrow + ((c << 5) ^ he));
    f32x16 s0 = qkchain(Kn, 0, qf);
    f32x16 s1 = qkchain(Kn, 1, qf);
    smhalf(s0, pa[0], pa[1]);
    __builtin_amdgcn_s_setprio(0);
    __builtin_amdgcn_sched_barrier(0);
    __builtin_amdgcn_s_barrier();
    __builtin_amdgcn_sched_barrier(0);

    gld16(VgC + vb + (size_t)(t + 1) * 128 + voff[0], VsC + ldso[0]);
    gld16(VgC + vb + (size_t)(t + 1) * 128 + voff[1], VsC + ldso[1]);
    if (t < 14) {
      gld16(KgC + kb + (size_t)(t + 2) * 8192 + koff[0], Kc + ldso[0]);
      gld16(KgC + kb + (size_t)(t + 2) * 8192 + koff[1], Kc + ldso[1]);
    }
    __builtin_amdgcn_sched_barrier(0);
    smhalf(s1, pa[2], pa[3]);
    __builtin_amdgcn_sched_barrier(0);
    asm volatile("s_waitcnt vmcnt(0)" ::: "memory");
    __builtin_amdgcn_sched_barrier(0);
    __builtin_amdgcn_s_barrier();
    __builtin_amdgcn_sched_barrier(0);

    char* tmp = Kc;
    Kc = Kn;
    Kn = tmp;
  }

#pragma unroll
  for (int c = 0; c < 4; ++c) {
    lacc = __builtin_amdgcn_mfma_f32_32x32x16_bf16(pa[c], ones, lacc, 0, 0, 0);
    bf16x8 vf0 = *(const bf16x8*)(VsC + rb + ((c << 5) ^ he));
    oacc[0] = __builtin_amdgcn_mfma_f32_32x32x16_bf16(pa[c], vf0, oacc[0], 0, 0, 0);
    bf16x8 vf1 = *(const bf16x8*)(VsC + 4096 + rb + ((c << 5) ^ he));
    oacc[1] = __builtin_amdgcn_mfma_f32_32x32x16_bf16(pa[c], vf1, oacc[1], 0, 0, 0);
  }

  const size_t pbase = (size_t)(kvh * 32 + bh) * 2048;
  if (l31 == 0) {
#pragma unroll
    for (int g = 0; g < 16; ++g)
      Lp[pbase + q0 + w * 32 + (g & 3) + 8 * (g >> 2) + 4 * lh] = lacc[g];
  }
  __bf16* Ob0 = Opart + pbase * 64;
#pragma unroll
  for (int dvt = 0; dvt < 2; ++dvt) {
#pragma unroll
    for (int g = 0; g < 16; ++g) {
      int s = q0 + w * 32 + (g & 3) + 8 * (g >> 2) + 4 * lh;
      Ob0[(size_t)s * 64 + dvt * 32 + l31] = (__bf16)oacc[dvt][g];
    }
  }
}

// ---------------- host ----------------

extern "C" void kernel_launch(void* const* d_in, const int* in_sizes, int n_in,
                              void* d_out, int out_size, void* d_ws, size_t ws_size,
                              hipStream_t stream) {
  const float* x1 = (const float*)d_in[0];
  const float* x2 = (const float*)d_in[1];
  const float* x3 = (const float*)d_in[2];
  const float* Wq = (const float*)d_in[3];
  const float* Wk = (const float*)d_in[4];
  const float* Wv = (const float*)d_in[5];
  const float* Wo = (const float*)d_in[6];
  const float* bo = (const float*)d_in[7];
  float* out = (float*)d_out;
  char* ws = (char*)d_ws;
  const size_t MB = 1ull << 20;
  __bf16* WT = (__bf16*)(ws + 24 * MB);
  __bf16* Qb = (__bf16*)(ws + 26 * MB);
  __bf16* Kb = (__bf16*)(ws + 34 * MB);
  __bf16* Vtb = (__bf16*)(ws + 42 * MB);
  __bf16* Opart = (__bf16*)(ws + 58 * MB);
  float* Lp = (float*)(ws + 74 * MB);

  cvt_w<<<dim3(256), 256, 0, stream>>>(Wq, Wk, Wv, Wo, WT);
  gemm_proj<<<dim3(256, 1, 3), 256, 0, stream>>>(x1, x2, x3, WT, Qb, Kb, Vtb);
  attn<<<dim3(1024), 256, 0, stream>>>(Qb, Kb, Vtb, Opart, Lp);
  gemm_out<<<dim3(512), 256, 0, stream>>>(Opart, Lp, WT + 3ull * 512 * 512, bo, out);
}